// Round 13
// baseline (88.226 us; speedup 1.0000x reference)
//
#include <hip/hip_runtime.h>

typedef __attribute__((ext_vector_type(8))) short   bf16x8;
typedef __attribute__((ext_vector_type(4))) float   f32x4;
typedef __attribute__((ext_vector_type(4))) unsigned int u32x4;

#define HT    8        // output rows per tile
#define WT    32       // output w columns per tile
#define WSPAN 34       // staged w columns: WT + 2 halo
#define NR    10       // staged rows: HT + 2
#define HALF  (NR * WSPAN * 4)   // u32x4 elements per LDS half

__device__ __forceinline__ unsigned short f2bf(float f) {
    union { float f; unsigned u; } v; v.f = f;
    unsigned u = v.u;
    u += 0x7FFFu + ((u >> 16) & 1u);   // RNE
    return (unsigned short)(u >> 16);
}

// Fused conv, 2 tiles per block (n-pair), double-buffered LDS halves:
// tile1's staging (issue + ds_write) is interleaved with tile0's compute, so
// in steady state staging latency is fully hidden behind MFMA. One barrier
// per tile. 43.5 KB LDS -> 3 blocks/CU.
__global__ __launch_bounds__(256, 3)
void conv3x3_fused(const float* __restrict__ x, const float* __restrict__ wk,
                   float* __restrict__ out) {
    const int hb = blockIdx.x, wq4 = blockIdx.y, nz = blockIdx.z;
    const int n0 = nz * 2, n1 = nz * 2 + 1;
    const int H0 = hb * HT, W0 = wq4 * WT;
    const int tid  = threadIdx.x;
    const int lane = tid & 63, wid = tid >> 6;
    const int lq = lane >> 4, lr = lane & 15;

    __shared__ u32x4 lds[2 * HALF];   // 43,520 B

    // ---- staging task: 136 tasks/row (34 wq x 4 c-octets), threads 0..135 ----
    const bool act = (tid < 136);
    const int cb = (tid < 128) ? (tid >> 5) : ((tid - 128) >> 1);
    const int wq = (tid < 128) ? (tid & 31) : (32 + ((tid - 128) & 1));

    auto issue_loads = [&](int rg, int nn, float (&dst)[8]) {
        const int wg = W0 - 1 + wq;
        const bool ok = act && ((unsigned)rg < 128u) && ((unsigned)wg < 128u);
        const float* p = x + (((nn * 32 + cb * 8) * 128 + rg) * 128 + wg);
        #pragma unroll
        for (int j = 0; j < 8; ++j)
            dst[j] = ok ? p[j * 16384] : 0.0f;   // channel stride = H*W
    };
    // swizzle f=(wq>>1)&3: measured conflict-free (R3/R10: SQ_LDS_BANK_CONFLICT=0)
    auto lds_write = [&](int half, int row, const float (&src)[8]) {
        if (!act) return;
        const int f = (wq >> 1) & 3;
        u32x4 pk;
        pk[0] = (unsigned)f2bf(src[0]) | ((unsigned)f2bf(src[1]) << 16);
        pk[1] = (unsigned)f2bf(src[2]) | ((unsigned)f2bf(src[3]) << 16);
        pk[2] = (unsigned)f2bf(src[4]) | ((unsigned)f2bf(src[5]) << 16);
        pk[3] = (unsigned)f2bf(src[6]) | ((unsigned)f2bf(src[7]) << 16);
        lds[half * HALF + (row * WSPAN + wq) * 4 + (cb ^ f)] = pk;
    };
    auto frag_read = [&](int half, int row, int w) -> bf16x8 {
        const int f = (w >> 1) & 3;
        union { u32x4 u; bf16x8 v; } cv;
        cv.u = lds[half * HALF + (row * WSPAN + w) * 4 + (lq ^ f)];
        return cv.v;
    };

    float buf[4][8];

#define STAGE(HF, R, NN)                                                      \
    {                                                                         \
        lds_write((HF), (R), buf[(R) & 3]);                                   \
        if ((R) + 4 < NR) issue_loads(H0 + (R) + 3, (NN), buf[(R) & 3]);      \
    }

    // ---- tile0 staging: 4-deep pipeline, zero barriers ----
    issue_loads(H0 - 1, n0, buf[0]);
    issue_loads(H0,     n0, buf[1]);
    issue_loads(H0 + 1, n0, buf[2]);
    issue_loads(H0 + 2, n0, buf[3]);
    STAGE(0, 0, n0) STAGE(0, 1, n0) STAGE(0, 2, n0) STAGE(0, 3, n0)
    STAGE(0, 4, n0) STAGE(0, 5, n0) STAGE(0, 6, n0) STAGE(0, 7, n0)
    STAGE(0, 8, n0) STAGE(0, 9, n0)

    // ---- weights -> registers: wave `wid` owns och tile [wid*16, wid*16+16) ----
    // Raw buffer index: ((c*3+ki)*3+kj)*64 + o   (reshape quirk).
    bf16x8 wA[9];
    #pragma unroll
    for (int p = 0; p < 9; ++p) {
        const int ki = p / 3, kj = p % 3;
        union { bf16x8 v; unsigned short s[8]; } u;
        #pragma unroll
        for (int j = 0; j < 8; ++j) {
            const int c = lq * 8 + j;
            u.s[j] = f2bf(wk[((c * 3 + ki) * 3 + kj) * 64 + wid * 16 + lr]);
        }
        wA[p] = u.v;
    }

    // ---- accumulators: 3-row ring x 2 pixel groups ----
    f32x4 acc[3][2];
    const f32x4 zero = {0.f, 0.f, 0.f, 0.f};
    #pragma unroll
    for (int a = 0; a < 3; ++a)
        #pragma unroll
        for (int pg = 0; pg < 2; ++pg) acc[a][pg] = zero;

    // per-thread output bases: o = wid*16 + lq*4 (+j), w = W0 + lr (+pg*16)
    float* obase0 = out + (((size_t)(n0 * 64 + wid * 16 + lq * 4) * 128) * 128) + W0 + lr;
    float* obase1 = out + (((size_t)(n1 * 64 + wid * 16 + lq * 4) * 128) * 128) + W0 + lr;

    // staged row RHO (zero-filled if OOB) feeds h = H0+RHO-ki; row h completes
    // at RHO = h-H0+2. All indices literal.
#define ROW(HF, RHO, OB)                                                      \
    {                                                                         \
        _Pragma("unroll")                                                     \
        for (int pg = 0; pg < 2; ++pg) {                                      \
            const bf16x8 fb0 = frag_read((HF), (RHO), pg * 16 + lr + 0);      \
            const bf16x8 fb1 = frag_read((HF), (RHO), pg * 16 + lr + 1);      \
            const bf16x8 fb2 = frag_read((HF), (RHO), pg * 16 + lr + 2);      \
            _Pragma("unroll")                                                 \
            for (int ki = 0; ki < 3; ++ki) {                                  \
                if ((RHO) - ki < 0 || (RHO) - ki > HT - 1) continue;          \
                const int a = ((RHO) - ki + 1) % 3;                           \
                acc[a][pg] = __builtin_amdgcn_mfma_f32_16x16x32_bf16(         \
                    wA[ki * 3 + 0], fb0, acc[a][pg], 0, 0, 0);                \
                acc[a][pg] = __builtin_amdgcn_mfma_f32_16x16x32_bf16(         \
                    wA[ki * 3 + 1], fb1, acc[a][pg], 0, 0, 0);                \
                acc[a][pg] = __builtin_amdgcn_mfma_f32_16x16x32_bf16(         \
                    wA[ki * 3 + 2], fb2, acc[a][pg], 0, 0, 0);                \
            }                                                                 \
        }                                                                     \
        if ((RHO) >= 2) {                                                     \
            const int h = H0 + (RHO) - 2;                                     \
            const int a = ((RHO) - 1) % 3;                                    \
            _Pragma("unroll")                                                 \
            for (int pg = 0; pg < 2; ++pg) {                                  \
                _Pragma("unroll")                                             \
                for (int j = 0; j < 4; ++j)                                   \
                    (OB)[(j * 128 + h) * 128 + pg * 16] = acc[a][pg][j];      \
                acc[a][pg] = zero;                                            \
            }                                                                 \
        }                                                                     \
    }

    __syncthreads();   // barrier 1: half0 ready

    // ---- compute tile0 (half0) interleaved with tile1 staging (half1) ----
    ROW(0, 0, obase0)
    issue_loads(H0 - 1, n1, buf[0]);
    issue_loads(H0,     n1, buf[1]);
    ROW(0, 1, obase0)
    issue_loads(H0 + 1, n1, buf[2]);
    issue_loads(H0 + 2, n1, buf[3]);
    ROW(0, 2, obase0)
    STAGE(1, 0, n1) ROW(0, 3, obase0)
    STAGE(1, 1, n1) ROW(0, 4, obase0)
    STAGE(1, 2, n1) ROW(0, 5, obase0)
    STAGE(1, 3, n1) ROW(0, 6, obase0)
    STAGE(1, 4, n1) ROW(0, 7, obase0)
    STAGE(1, 5, n1) ROW(0, 8, obase0)
    STAGE(1, 6, n1) ROW(0, 9, obase0)
    STAGE(1, 7, n1) STAGE(1, 8, n1) STAGE(1, 9, n1)

    __syncthreads();   // barrier 2: half1 ready

    // ---- compute tile1 (half1) ----
    ROW(1, 0, obase1) ROW(1, 1, obase1) ROW(1, 2, obase1) ROW(1, 3, obase1)
    ROW(1, 4, obase1) ROW(1, 5, obase1) ROW(1, 6, obase1) ROW(1, 7, obase1)
    ROW(1, 8, obase1) ROW(1, 9, obase1)
#undef ROW
#undef STAGE
}

extern "C" void kernel_launch(void* const* d_in, const int* in_sizes, int n_in,
                              void* d_out, int out_size, void* d_ws, size_t ws_size,
                              hipStream_t stream) {
    const float* x  = (const float*)d_in[0];
    const float* wk = (const float*)d_in[1];
    float* out = (float*)d_out;
    dim3 grid(16, 4, 16);   // hb, w-quarter, n-pair  -> 1024 blocks x 2 tiles
    dim3 block(256);
    conv3x3_fused<<<grid, block, 0, stream>>>(x, wk, out);
}

// Round 14
// 44.085 us; speedup vs baseline: 2.0013x; 2.0013x over previous
//
#include <hip/hip_runtime.h>

typedef __attribute__((ext_vector_type(8))) short   bf16x8;
typedef __attribute__((ext_vector_type(4))) float   f32x4;
typedef __attribute__((ext_vector_type(4))) unsigned int u32x4;

#define HT    8        // output rows per block
#define WT    32       // output w columns per block
#define WSPAN 34       // staged w columns: WT + 2 halo
#define NR    10       // staged rows: HT + 2

__device__ __forceinline__ unsigned short f2bf(float f) {
    union { float f; unsigned u; } v; v.f = f;
    unsigned u = v.u;
    u += 0x7FFFu + ((u >> 16) & 1u);   // RNE
    return (unsigned short)(u >> 16);
}

// Fused conv, 32-wide tiles, ALL-WAVE staging: wave-pair 0 (threads 0-127)
// stages even rows, pair 1 stages odd rows; the 8 halo tasks per row are
// spread one-per-thread (40 threads/pair) and issued at the prologue.
// ONE __syncthreads(), then barrier-free MFMA compute.
__global__ __launch_bounds__(256, 4)
void conv3x3_fused(const float* __restrict__ x, const float* __restrict__ wk,
                   float* __restrict__ out) {
    const int hb = blockIdx.x, wq4 = blockIdx.y, n = blockIdx.z;
    const int H0 = hb * HT, W0 = wq4 * WT;
    const int tid  = threadIdx.x;
    const int lane = tid & 63, wid = tid >> 6;
    const int lq = lane >> 4, lr = lane & 15;

    __shared__ u32x4 lds[NR * WSPAN * 4];   // 21,760 B

    // ---- staging decomposition ----
    // pair p = tid>>7 stages rows rho = 2k+p (k=0..4).
    // main task (all 128 pair-threads): cb = t>>5, wq = t&31.
    // halo tasks (t<40): one task each: row k=t>>3, cb=(t&7)>>1, wq=32+(t&1).
    const int pairId = tid >> 7, t = tid & 127;
    const int cb = t >> 5, wq = t & 31;
    const bool hasH = (t < 40);
    const int hk = t >> 3, hcb = (t & 7) >> 1, hwq = 32 + (t & 1);

    auto issue_loads = [&](int rg, int icb, int iwq, float (&dst)[8]) {
        const int wg = W0 - 1 + iwq;
        const bool ok = ((unsigned)rg < 128u) && ((unsigned)wg < 128u);
        const float* p = x + (((n * 32 + icb * 8) * 128 + rg) * 128 + wg);
        #pragma unroll
        for (int j = 0; j < 8; ++j)
            dst[j] = ok ? p[j * 16384] : 0.0f;   // channel stride = H*W
    };
    // swizzle f=(wq>>1)&3: measured conflict-free (R3/R10/R11: 0 conflicts)
    auto lds_write = [&](int row, int icb, int iwq, const float (&src)[8]) {
        const int f = (iwq >> 1) & 3;
        u32x4 pk;
        pk[0] = (unsigned)f2bf(src[0]) | ((unsigned)f2bf(src[1]) << 16);
        pk[1] = (unsigned)f2bf(src[2]) | ((unsigned)f2bf(src[3]) << 16);
        pk[2] = (unsigned)f2bf(src[4]) | ((unsigned)f2bf(src[5]) << 16);
        pk[3] = (unsigned)f2bf(src[6]) | ((unsigned)f2bf(src[7]) << 16);
        lds[(row * WSPAN + iwq) * 4 + (icb ^ f)] = pk;
    };
    auto frag_read = [&](int row, int w) -> bf16x8 {
        const int f = (w >> 1) & 3;
        union { u32x4 u; bf16x8 v; } cv;
        cv.u = lds[(row * WSPAN + w) * 4 + (lq ^ f)];
        return cv.v;
    };

    // ---- stage: 5 rows per pair, 4-deep pipeline + 1-shot halo ----
    // pair's staged row for step k: rho = 2k+pairId, global rg = H0-1+rho.
    float buf[4][8], hbuf[8];
    issue_loads(H0 - 1 + pairId,     cb, wq, buf[0]);
    issue_loads(H0 - 1 + pairId + 2, cb, wq, buf[1]);
    issue_loads(H0 - 1 + pairId + 4, cb, wq, buf[2]);
    issue_loads(H0 - 1 + pairId + 6, cb, wq, buf[3]);
    if (hasH) issue_loads(H0 - 1 + 2 * hk + pairId, hcb, hwq, hbuf);

    lds_write(0 + pairId, cb, wq, buf[0]);
    issue_loads(H0 - 1 + pairId + 8, cb, wq, buf[0]);
    lds_write(2 + pairId, cb, wq, buf[1]);
    lds_write(4 + pairId, cb, wq, buf[2]);
    lds_write(6 + pairId, cb, wq, buf[3]);
    lds_write(8 + pairId, cb, wq, buf[0]);
    if (hasH) lds_write(2 * hk + pairId, hcb, hwq, hbuf);

    // ---- weights -> registers: wave `wid` owns och tile [wid*16, wid*16+16) ----
    // Raw buffer index: ((c*3+ki)*3+kj)*64 + o   (reshape quirk).
    bf16x8 wA[9];
    #pragma unroll
    for (int p = 0; p < 9; ++p) {
        const int ki = p / 3, kj = p % 3;
        union { bf16x8 v; unsigned short s[8]; } u;
        #pragma unroll
        for (int j = 0; j < 8; ++j) {
            const int c = lq * 8 + j;
            u.s[j] = f2bf(wk[((c * 3 + ki) * 3 + kj) * 64 + wid * 16 + lr]);
        }
        wA[p] = u.v;
    }

    __syncthreads();   // the ONLY barrier

    // ---- accumulators: 3-row ring x 2 pixel groups ----
    f32x4 acc[3][2];
    const f32x4 zero = {0.f, 0.f, 0.f, 0.f};
    #pragma unroll
    for (int a = 0; a < 3; ++a)
        #pragma unroll
        for (int pg = 0; pg < 2; ++pg) acc[a][pg] = zero;

    // per-thread output base: o = wid*16 + lq*4 (+j), w = W0 + lr (+pg*16)
    float* obase = out + (((size_t)(n * 64 + wid * 16 + lq * 4) * 128) * 128) + W0 + lr;

    // staged row RHO (zero-filled if OOB) feeds h = H0+RHO-ki; row h completes
    // at RHO = h-H0+2. All indices literal.
#define ROW(RHO)                                                              \
    {                                                                         \
        _Pragma("unroll")                                                     \
        for (int pg = 0; pg < 2; ++pg) {                                      \
            const bf16x8 fb0 = frag_read((RHO), pg * 16 + lr + 0);            \
            const bf16x8 fb1 = frag_read((RHO), pg * 16 + lr + 1);            \
            const bf16x8 fb2 = frag_read((RHO), pg * 16 + lr + 2);            \
            _Pragma("unroll")                                                 \
            for (int ki = 0; ki < 3; ++ki) {                                  \
                if ((RHO) - ki < 0 || (RHO) - ki > HT - 1) continue;          \
                const int a = ((RHO) - ki + 1) % 3;                           \
                acc[a][pg] = __builtin_amdgcn_mfma_f32_16x16x32_bf16(         \
                    wA[ki * 3 + 0], fb0, acc[a][pg], 0, 0, 0);                \
                acc[a][pg] = __builtin_amdgcn_mfma_f32_16x16x32_bf16(         \
                    wA[ki * 3 + 1], fb1, acc[a][pg], 0, 0, 0);                \
                acc[a][pg] = __builtin_amdgcn_mfma_f32_16x16x32_bf16(         \
                    wA[ki * 3 + 2], fb2, acc[a][pg], 0, 0, 0);                \
            }                                                                 \
        }                                                                     \
        if ((RHO) >= 2) {                                                     \
            const int h = H0 + (RHO) - 2;                                     \
            const int a = ((RHO) - 1) % 3;                                    \
            _Pragma("unroll")                                                 \
            for (int pg = 0; pg < 2; ++pg) {                                  \
                _Pragma("unroll")                                             \
                for (int j = 0; j < 4; ++j)                                   \
                    obase[(j * 128 + h) * 128 + pg * 16] = acc[a][pg][j];     \
                acc[a][pg] = zero;                                            \
            }                                                                 \
        }                                                                     \
    }

    ROW(0) ROW(1) ROW(2) ROW(3) ROW(4) ROW(5) ROW(6) ROW(7) ROW(8) ROW(9)
#undef ROW
}

extern "C" void kernel_launch(void* const* d_in, const int* in_sizes, int n_in,
                              void* d_out, int out_size, void* d_ws, size_t ws_size,
                              hipStream_t stream) {
    const float* x  = (const float*)d_in[0];
    const float* wk = (const float*)d_in[1];
    float* out = (float*)d_out;
    dim3 grid(16, 4, 32);   // hb, w-quarter, n  -> 2048 blocks
    dim3 block(256);
    conv3x3_fused<<<grid, block, 0, stream>>>(x, wk, out);
}